// Round 1
// baseline (292.344 us; speedup 1.0000x reference)
//
#include <hip/hip_runtime.h>
#include <hip/hip_bf16.h>
#include <cstddef>
#include <cstdint>

// ---------------- problem constants ----------------
#define M_TOK   16384      // 32*512 tokens
#define N_CODE  8192       // NUM_LATENTS
#define K_DIM   256        // LATENT_DIM
#define NSPLIT  4
#define BM      128
#define BN      128
#define BK      32         // R6: BK=32 so a double-buffered 4-array set fits 64 KB LDS
#define KSTEPS  (K_DIM / BK)            // 8
#define TILES   ((N_CODE / NSPLIT) / BN) // 16
#define TOTAL_STEPS (TILES * KSTEPS)    // 128

typedef short bf16x8 __attribute__((ext_vector_type(8)));  // 8 bf16 = 4 VGPRs
typedef float f32x4  __attribute__((ext_vector_type(4)));

__device__ __forceinline__ unsigned short f2bf_rne(float f) {
    unsigned u = __float_as_uint(f);
    unsigned r = u + 0x7FFFu + ((u >> 16) & 1u);
    return (unsigned short)(r >> 16);
}
__device__ __forceinline__ float bf2f(unsigned short h) {
    union { unsigned u; float f; } c; c.u = ((unsigned)h) << 16; return c.f;
}

__device__ __forceinline__ void gload16(const void* g, void* l) {
    __builtin_amdgcn_global_load_lds(
        (const __attribute__((address_space(1))) void*)g,
        (__attribute__((address_space(3))) void*)l, 16, 0, 0);
}

// ---------------- prep: bf16 hi/lo split + fp32 norms ----------------
__global__ void vq_prep(const float* __restrict__ x, const float* __restrict__ cb,
                        unsigned short* __restrict__ xh, unsigned short* __restrict__ xl,
                        unsigned short* __restrict__ wh, unsigned short* __restrict__ wl,
                        float* __restrict__ x2, float* __restrict__ w2) {
    int gt   = blockIdx.x * blockDim.x + threadIdx.x;
    int row  = gt >> 6;
    int lane = gt & 63;
    if (row >= M_TOK + N_CODE) return;
    const float* src; unsigned short *dh, *dl; float* dn;
    if (row < M_TOK) {
        src = x + (size_t)row * K_DIM;
        dh = xh + (size_t)row * K_DIM; dl = xl + (size_t)row * K_DIM; dn = x2 + row;
    } else {
        int r = row - M_TOK;
        src = cb + (size_t)r * K_DIM;
        dh = wh + (size_t)r * K_DIM; dl = wl + (size_t)r * K_DIM; dn = w2 + r;
    }
    float4 v = ((const float4*)src)[lane];
    unsigned short h0 = f2bf_rne(v.x), h1 = f2bf_rne(v.y);
    unsigned short h2 = f2bf_rne(v.z), h3 = f2bf_rne(v.w);
    unsigned short l0 = f2bf_rne(v.x - bf2f(h0)), l1 = f2bf_rne(v.y - bf2f(h1));
    unsigned short l2 = f2bf_rne(v.z - bf2f(h2)), l3 = f2bf_rne(v.w - bf2f(h3));
    ushort4 hv; hv.x = h0; hv.y = h1; hv.z = h2; hv.w = h3;
    ushort4 lv; lv.x = l0; lv.y = l1; lv.z = l2; lv.w = l3;
    ((ushort4*)dh)[lane] = hv;
    ((ushort4*)dl)[lane] = lv;
    float s = v.x*v.x + v.y*v.y + v.z*v.z + v.w*v.w;
    #pragma unroll
    for (int off = 32; off > 0; off >>= 1) s += __shfl_down(s, off);
    if (lane == 0) *dn = s;
}

// ---------------- main: pipelined 3-term bf16 MFMA GEMM fused with argmin ----------------
// R6: prefetch-pipelined double-buffered K-loop (T3-lite), BK=32.
//   per step: barrier -> issue STAGE(step+1) into buf^1 -> ds_read buf -> 48 MFMA.
//   The barrier's implicit vmcnt(0) drain is now covered by ~425 cyc of own compute
//   instead of being exposed (old stage/barrier/compute/barrier structure).
// Swizzle (64 B rows = 4 x 16B chunks): LDS slot for global chunk q at row r is
//   s = q ^ ((r>>1)&3). Within a 16-lane read phase (quad fixed) the pair
//   (r&1, s) covers all 8 bank-groups 2-way -> conflict-free (2-way is free).
//   Staging keeps the LDS dest LINEAR (global_load_lds requirement) and permutes
//   the global source chunk: lane fetches g = (lane&3) ^ ((lane>>3)&3).
// XCD swizzle (T1): split = xcd&3 so each XCD keeps ONE 2 MB codebook split
//   resident in its private 4 MB L2 (was: all 4 splits thrash every L2).
// Accumulation order per accumulator is the same K-slice sequence as R5
//   (kc*64 + ks*32  ==  kcs*32, kcs ascending) -> bit-exact scores.
__global__ __launch_bounds__(256, 2)
void vq_main_mfma(const unsigned short* __restrict__ xh, const unsigned short* __restrict__ xl,
                  const unsigned short* __restrict__ wh, const unsigned short* __restrict__ wl,
                  const float* __restrict__ x2, const float* __restrict__ w2,
                  float* __restrict__ pminv, int* __restrict__ pmini) {
    // [2 dbuf][4 arrays: xh,xl,wh,wl][128 rows][32 bf16] = 64 KB
    __shared__ __align__(1024) unsigned short sbuf[2][4][BM][BK];
    __shared__ float red_d[BM][2];
    __shared__ int   red_i[BM][2];

    // XCD-aware remap (bijective: 512 blocks, 8 XCDs, 64 each)
    const int fid   = blockIdx.y * NSPLIT + blockIdx.x;  // dispatch order, x fastest
    const int xcd   = fid & 7;
    const int jj    = fid >> 3;              // 0..63
    const int split = xcd & 3;
    const int mtile = ((xcd >> 2) << 6) + jj;
    const int gm    = mtile * BM;

    const int tid   = threadIdx.x;
    const int w     = tid >> 6;              // wave 0..3
    const int lane  = tid & 63;
    const int wr    = w >> 1;                // row half (0/1)
    const int wc    = w & 1;                 // col half (0/1)
    const int quad  = lane >> 4;             // 0..3
    const int l15   = lane & 15;

    // staging: wave w covers rows [w*32, w*32+32) of each array, 2 instrs of 16 rows.
    const int w32   = w * 32;
    const int srow  = lane >> 2;                       // 0..15 within 16-row group
    const int sg    = (lane & 3) ^ ((lane >> 3) & 3);  // pre-swizzled global chunk

    // per-lane row constants
    float x2r[16];
    #pragma unroll
    for (int rt = 0; rt < 4; ++rt)
        #pragma unroll
        for (int reg = 0; reg < 4; ++reg)
            x2r[rt*4+reg] = x2[gm + wr*64 + rt*16 + quad*4 + reg];

    float minv[16];
    int   mini[16];
    #pragma unroll
    for (int i = 0; i < 16; ++i) { minv[i] = 3.4e38f; mini[i] = 0; }

    const char* xhp = (const char*)xh;
    const char* xlp = (const char*)xl;
    const char* whp = (const char*)wh;
    const char* wlp = (const char*)wl;

    // per-lane constant parts of global staging offsets (bytes)
    const size_t xr0 = (size_t)(gm + w32 + srow) * (K_DIM*2) + (size_t)sg*16;
    const size_t xr1 = xr0 + (size_t)16 * (K_DIM*2);
    const size_t wrb0 = (size_t)(w32 + srow) * (K_DIM*2) + (size_t)sg*16;  // + nb*512 + ko
    const size_t wrb1 = wrb0 + (size_t)16 * (K_DIM*2);
    const unsigned ls0 = (unsigned)w32 * (BK*2);       // wave-uniform LDS base offset

    #define STAGE(stepv)                                                            \
    do {                                                                            \
        const int   t_   = (stepv) >> 3;                                            \
        const int   kcs_ = (stepv) & 7;                                             \
        const int   b_   = (stepv) & 1;                                             \
        const size_t ko_  = (size_t)kcs_ * (BK*2);                                  \
        const size_t nbo_ = ((size_t)(split*(N_CODE/NSPLIT) + t_*BN)) * (K_DIM*2);  \
        char* p0 = (char*)&sbuf[b_][0][0][0] + ls0;                                 \
        char* p1 = (char*)&sbuf[b_][1][0][0] + ls0;                                 \
        char* p2 = (char*)&sbuf[b_][2][0][0] + ls0;                                 \
        char* p3 = (char*)&sbuf[b_][3][0][0] + ls0;                                 \
        gload16(xhp + xr0 + ko_,        p0);                                        \
        gload16(xhp + xr1 + ko_,        p0 + 1024);                                 \
        gload16(xlp + xr0 + ko_,        p1);                                        \
        gload16(xlp + xr1 + ko_,        p1 + 1024);                                 \
        gload16(whp + nbo_ + wrb0 + ko_, p2);                                       \
        gload16(whp + nbo_ + wrb1 + ko_, p2 + 1024);                                \
        gload16(wlp + nbo_ + wrb0 + ko_, p3);                                       \
        gload16(wlp + nbo_ + wrb1 + ko_, p3 + 1024);                                \
    } while (0)

    STAGE(0);                                  // prologue prefetch

    const int sl = quad ^ ((l15 >> 1) & 3);    // swizzled read slot (0..3)

    for (int tile = 0; tile < TILES; ++tile) {
        f32x4 acc[4][4];
        #pragma unroll
        for (int rt = 0; rt < 4; ++rt)
            #pragma unroll
            for (int ct = 0; ct < 4; ++ct)
                acc[rt][ct] = (f32x4){0.f, 0.f, 0.f, 0.f};

        #pragma unroll 2
        for (int kcs = 0; kcs < KSTEPS; ++kcs) {
            const int step = tile * KSTEPS + kcs;
            // one barrier per step: drains STAGE(step) (vmcnt0) and orders
            // last iteration's ds_reads of buf^1 before STAGE(step+1) overwrites it
            __syncthreads();
            if (step + 1 < TOTAL_STEPS) STAGE(step + 1);

            const int b = kcs & 1;             // == step&1 (KSTEPS even)
            const char* xhb = (const char*)&sbuf[b][0][0][0];
            const char* xlb = (const char*)&sbuf[b][1][0][0];
            const char* whb = (const char*)&sbuf[b][2][0][0];
            const char* wlb = (const char*)&sbuf[b][3][0][0];

            bf16x8 ah[4], al[4], bh[4], bl[4];
            #pragma unroll
            for (int rt = 0; rt < 4; ++rt) {
                const int off = (wr*64 + rt*16 + l15) * (BK*2) + sl*16;
                ah[rt] = *(const bf16x8*)(xhb + off);
                al[rt] = *(const bf16x8*)(xlb + off);
            }
            #pragma unroll
            for (int ct = 0; ct < 4; ++ct) {
                const int off = (wc*64 + ct*16 + l15) * (BK*2) + sl*16;
                bh[ct] = *(const bf16x8*)(whb + off);
                bl[ct] = *(const bf16x8*)(wlb + off);
            }

            __builtin_amdgcn_s_setprio(1);     // T5: pipeline gives waves role-split
            #pragma unroll
            for (int rt = 0; rt < 4; ++rt)
                #pragma unroll
                for (int ct = 0; ct < 4; ++ct) {
                    acc[rt][ct] = __builtin_amdgcn_mfma_f32_16x16x32_bf16(al[rt], bh[ct], acc[rt][ct], 0, 0, 0);
                    acc[rt][ct] = __builtin_amdgcn_mfma_f32_16x16x32_bf16(ah[rt], bl[ct], acc[rt][ct], 0, 0, 0);
                    acc[rt][ct] = __builtin_amdgcn_mfma_f32_16x16x32_bf16(ah[rt], bh[ct], acc[rt][ct], 0, 0, 0);
                }
            __builtin_amdgcn_s_setprio(0);
        }

        // score tile: dist = (x2 - 2*xw) + w2, C layout col=lane&15, row=quad*4+reg
        const int nb = split * (N_CODE / NSPLIT) + tile * BN;
        float w2c[4];
        int   cidx[4];
        #pragma unroll
        for (int ct = 0; ct < 4; ++ct) {
            cidx[ct] = nb + wc*64 + ct*16 + l15;
            w2c[ct]  = w2[cidx[ct]];
        }
        #pragma unroll
        for (int rt = 0; rt < 4; ++rt)
            #pragma unroll
            for (int ct = 0; ct < 4; ++ct) {
                #pragma unroll
                for (int reg = 0; reg < 4; ++reg) {
                    float d = (x2r[rt*4+reg] - 2.0f * acc[rt][ct][reg]) + w2c[ct];
                    int r16 = rt*4 + reg;
                    if (d < minv[r16]) { minv[r16] = d; mini[r16] = cidx[ct]; }
                }
            }
    }
    #undef STAGE

    // reduce across the 16 lanes (same rows, different cols); tie-break lower index
    #pragma unroll
    for (int r16 = 0; r16 < 16; ++r16) {
        float d  = minv[r16];
        int   ix = mini[r16];
        #pragma unroll
        for (int off = 1; off < 16; off <<= 1) {
            float od = __shfl_xor(d, off);
            int   oi = __shfl_xor(ix, off);
            if (od < d || (od == d && oi < ix)) { d = od; ix = oi; }
        }
        if (l15 == 0) {
            int row_local = wr*64 + (r16 >> 2)*16 + quad*4 + (r16 & 3);
            red_d[row_local][wc] = d;
            red_i[row_local][wc] = ix;
        }
    }
    __syncthreads();
    // combine the two col-halves, write per-split partials
    if (tid < BM) {
        float d0 = red_d[tid][0], d1 = red_d[tid][1];
        int   i0 = red_i[tid][0], i1 = red_i[tid][1];
        float d; int ix;
        if (d1 < d0 || (d1 == d0 && i1 < i0)) { d = d1; ix = i1; } else { d = d0; ix = i0; }
        pminv[(size_t)(gm + tid) * NSPLIT + split] = d;
        pmini[(size_t)(gm + tid) * NSPLIT + split] = ix;
    }
}

// ---------------- epilogue: reduce NSPLIT partials in-wave, then z_q/z/x/indices ----------------
__global__ void vq_gather(const float* __restrict__ x, const float* __restrict__ cb,
                          const float* __restrict__ pminv, const int* __restrict__ pmini,
                          float* __restrict__ out) {
    int t = blockIdx.x * blockDim.x + threadIdx.x;   // float4 units
    int m = t >> 6;
    int q = t & 63;        // == lane: one wave handles exactly one row

    // NSPLIT-way split reduce, replicated across lanes via xor shuffles
    float d  = pminv[(size_t)m * NSPLIT + (q & (NSPLIT-1))];
    int   ix = pmini[(size_t)m * NSPLIT + (q & (NSPLIT-1))];
    #pragma unroll
    for (int off = 1; off < NSPLIT; off <<= 1) {
        float od = __shfl_xor(d, off);
        int   oi = __shfl_xor(ix, off);
        if (od < d || (od == d && oi < ix)) { d = od; ix = oi; }
    }

    float4 xv = ((const float4*)x)[t];
    float4 zv = ((const float4*)cb)[(size_t)ix * 64 + q];
    float4 zq;
    zq.x = xv.x + (zv.x - xv.x);
    zq.y = xv.y + (zv.y - xv.y);
    zq.z = xv.z + (zv.z - xv.z);
    zq.w = xv.w + (zv.w - xv.w);
    float4* o = (float4*)out;
    const int ELEM4 = M_TOK * 64;
    o[t]           = zq;     // z_q
    o[t + ELEM4]   = zv;     // z
    o[t + 2*ELEM4] = xv;     // x
    if (q == 0) out[(size_t)3 * M_TOK * K_DIM + m] = (float)ix;
}

// ---------------- launcher ----------------
extern "C" void kernel_launch(void* const* d_in, const int* in_sizes, int n_in,
                              void* d_out, int out_size, void* d_ws, size_t ws_size,
                              hipStream_t stream) {
    const float* x  = (const float*)d_in[0];   // 16384 x 256
    const float* cb = (const float*)d_in[1];   // 8192 x 256
    float* out = (float*)d_out;

    // workspace layout
    char* p = (char*)d_ws;
    unsigned short* xh = (unsigned short*)p;  p += (size_t)M_TOK  * K_DIM * 2;  // 8 MB
    unsigned short* xl = (unsigned short*)p;  p += (size_t)M_TOK  * K_DIM * 2;  // 8 MB
    unsigned short* wh = (unsigned short*)p;  p += (size_t)N_CODE * K_DIM * 2;  // 4 MB
    unsigned short* wl = (unsigned short*)p;  p += (size_t)N_CODE * K_DIM * 2;  // 4 MB
    float* x2    = (float*)p;  p += (size_t)M_TOK * 4;
    float* w2    = (float*)p;  p += (size_t)N_CODE * 4;
    float* pminv = (float*)p;  p += (size_t)M_TOK * NSPLIT * 4;
    int*   pmini = (int*)p;    p += (size_t)M_TOK * NSPLIT * 4;

    // prep: one wave per row, 24576 rows
    {
        int waves = M_TOK + N_CODE;
        vq_prep<<<(waves * 64 + 255) / 256, 256, 0, stream>>>(x, cb, xh, xl, wh, wl, x2, w2);
    }
    // main fused MFMA GEMM + argmin (pipelined double-buffer, XCD-swizzled)
    {
        dim3 grid(NSPLIT, M_TOK / BM);   // 4 x 128 = 512 blocks
        vq_main_mfma<<<grid, 256, 0, stream>>>(xh, xl, wh, wl, x2, w2, pminv, pmini);
    }
    // epilogue (split-reduce fused in)
    {
        int t = M_TOK * (K_DIM / 4);     // 1048576 float4 threads
        vq_gather<<<t / 256, 256, 0, stream>>>(x, cb, pminv, pmini, out);
    }
}